// Round 1
// baseline (482.922 us; speedup 1.0000x reference)
//
#include <hip/hip_runtime.h>

#define Bn 16384
#define Tn 2
#define Nn 100
#define Sn 6
#define Hn 16

__device__ __forceinline__ float frcp(float v) { return __builtin_amdgcn_rcpf(v); }
__device__ __forceinline__ float fsig(float v) { return frcp(1.0f + __expf(-v)); }
__device__ __forceinline__ float ftanh(float v) {
    v = fminf(fmaxf(v, -15.0f), 15.0f);
    float e = __expf(-2.0f * v);
    return (1.0f - e) * frcp(1.0f + e);
}

__device__ __forceinline__ float head_mlp(
    const float h[16],
    const float* __restrict__ wa1, const float* __restrict__ b1,
    const float* __restrict__ wa2, const float* __restrict__ b2,
    const float* __restrict__ wa3, float b3)
{
    float v1[16];
#pragma unroll
    for (int j = 0; j < 16; ++j) {
        float acc = b1[j];
#pragma unroll
        for (int k = 0; k < 16; ++k) acc = fmaf(h[k], wa1[j * 16 + k], acc);
        v1[j] = fmaxf(acc, 0.0f);
    }
    float v2[16];
#pragma unroll
    for (int j = 0; j < 16; ++j) {
        float acc = b2[j];
#pragma unroll
        for (int k = 0; k < 16; ++k) acc = fmaf(v1[k], wa2[j * 16 + k], acc);
        v2[j] = fmaxf(acc, 0.0f);
    }
    float acc = b3;
#pragma unroll
    for (int k = 0; k < 16; ++k) acc = fmaf(v2[k], wa3[k], acc);
    return fmaxf(acc, 0.0f);
}

__global__ __launch_bounds__(256) void stage1_kernel(
    const float* __restrict__ x,
    const float* __restrict__ Wih, const float* __restrict__ Whh,
    const float* __restrict__ bih, const float* __restrict__ bhh,
    const float* __restrict__ Wa1, const float* __restrict__ ba1,
    const float* __restrict__ Wa2, const float* __restrict__ ba2,
    const float* __restrict__ Wa3, const float* __restrict__ ba3,
    float* __restrict__ out0, float* __restrict__ pbuf)
{
    const int n = blockIdx.y;
    const int b = blockIdx.x * 256 + threadIdx.x;

    // wave-uniform weight bases -> compiler scalarizes to s_load
    const float* wih = Wih + n * 288;
    const float* whh = Whh + n * 768;
    const float* bi  = bih + n * 48;
    const float* bh  = bhh + n * 48;
    const float* wa1 = Wa1 + n * 256;
    const float* wa2 = Wa2 + n * 256;
    const float* wa3 = Wa3 + n * 16;
    const float* bb1 = ba1 + n * 16;
    const float* bb2 = ba2 + n * 16;
    const float  bb3 = ba3[n];

    // x[b, t, n, 0:6] for t = 0,1  (24B chunks, float2-aligned)
    float xv[2][6];
    {
        const float* xb = x + (size_t)b * (Tn * Nn * Sn) + n * Sn;
#pragma unroll
        for (int t = 0; t < 2; ++t) {
            const float2* p2 = (const float2*)(xb + t * (Nn * Sn));
            float2 a = p2[0], c = p2[1], d = p2[2];
            xv[t][0] = a.x; xv[t][1] = a.y;
            xv[t][2] = c.x; xv[t][3] = c.y;
            xv[t][4] = d.x; xv[t][5] = d.y;
        }
    }

    float h[16], outv[2];

    // ---- t = 0 : h_prev == 0 -> gh = b_hh (skip 768 FMAs) ----
#pragma unroll
    for (int j = 0; j < 16; ++j) {
        float ir = bi[j], iz = bi[16 + j], inn = bi[32 + j];
#pragma unroll
        for (int s = 0; s < 6; ++s) {
            ir  = fmaf(xv[0][s], wih[j * 6 + s], ir);
            iz  = fmaf(xv[0][s], wih[(16 + j) * 6 + s], iz);
            inn = fmaf(xv[0][s], wih[(32 + j) * 6 + s], inn);
        }
        float r  = fsig(ir + bh[j]);
        float z  = fsig(iz + bh[16 + j]);
        float nn = ftanh(inn + r * bh[32 + j]);
        h[j] = (1.0f - z) * nn;
    }
    outv[0] = head_mlp(h, wa1, bb1, wa2, bb2, wa3, bb3);

    // ---- t = 1 ----
    {
        float hnew[16];
#pragma unroll
        for (int j = 0; j < 16; ++j) {
            float ir = bi[j], iz = bi[16 + j], inn = bi[32 + j];
#pragma unroll
            for (int s = 0; s < 6; ++s) {
                ir  = fmaf(xv[1][s], wih[j * 6 + s], ir);
                iz  = fmaf(xv[1][s], wih[(16 + j) * 6 + s], iz);
                inn = fmaf(xv[1][s], wih[(32 + j) * 6 + s], inn);
            }
            float hr = bh[j], hz = bh[16 + j], hn = bh[32 + j];
#pragma unroll
            for (int k = 0; k < 16; ++k) {
                hr = fmaf(h[k], whh[j * 16 + k], hr);
                hz = fmaf(h[k], whh[(16 + j) * 16 + k], hz);
                hn = fmaf(h[k], whh[(32 + j) * 16 + k], hn);
            }
            float r  = fsig(ir + hr);
            float z  = fsig(iz + hz);
            float nn = ftanh(inn + r * hn);
            hnew[j] = (1.0f - z) * nn + z * h[j];
        }
#pragma unroll
        for (int j = 0; j < 16; ++j) h[j] = hnew[j];
    }
    outv[1] = head_mlp(h, wa1, bb1, wa2, bb2, wa3, bb3);

    // ---- scatter through the transpose/reshape permutation ----
    // a[b,t,n] sits at flat k0 = n*B*T + b*T + t; p[b2,t2,n2] = flat[b2*200+t2*100+n2]
#pragma unroll
    for (int t = 0; t < 2; ++t) {
        unsigned k0 = (unsigned)n * (Bn * Tn) + (unsigned)b * 2u + (unsigned)t;
        unsigned b2 = k0 / 200u;
        unsigned r  = k0 - b2 * 200u;
        unsigned t2 = (r >= 100u) ? 1u : 0u;
        unsigned n2 = r - t2 * 100u;
        float v = outv[t];
        if (t2) out0[b2 * 100u + n2] = v;           // output 0 = p[:, 1, :]
        if (n2 == 99u)      pbuf[b2 * 6u + t2 * 3u + 0u] = v;
        else if (n2 == 89u) pbuf[b2 * 6u + t2 * 3u + 1u] = v;
        else if (n2 == 98u) pbuf[b2 * 6u + t2 * 3u + 2u] = v;
    }
}

__global__ __launch_bounds__(256) void stage2_kernel(
    const float* __restrict__ x, const float* __restrict__ pbuf,
    const float* __restrict__ Wl1, const float* __restrict__ bl1,
    const float* __restrict__ Wl2, const float* __restrict__ bl2,
    const float* __restrict__ Wl3, const float* __restrict__ bl3,
    const float* __restrict__ Wihc, const float* __restrict__ Whhc,
    const float* __restrict__ bihc, const float* __restrict__ bhhc,
    const float* __restrict__ Wc1, const float* __restrict__ bc1,
    const float* __restrict__ Wc2, const float* __restrict__ bc2,
    const float* __restrict__ Wc3, const float* __restrict__ bc3,
    float* __restrict__ out1)
{
    const int b = blockIdx.x * 256 + threadIdx.x;
    if (b >= Bn) return;

    // xi nonzero columns: 0..6 -> ch99, 7..13 -> ch89, 28..34 -> ch98 (14..27 are zero)
    float u[2][21];
#pragma unroll
    for (int t = 0; t < 2; ++t) {
        const float* xb = x + (size_t)b * (Tn * Nn * Sn) + t * (Nn * Sn);
#pragma unroll
        for (int s = 0; s < 6; ++s) {
            u[t][s]      = xb[99 * 6 + s];
            u[t][7 + s]  = xb[89 * 6 + s];
            u[t][14 + s] = xb[98 * 6 + s];
        }
        u[t][6]  = pbuf[b * 6 + t * 3 + 0];
        u[t][13] = pbuf[b * 6 + t * 3 + 1];
        u[t][20] = pbuf[b * 6 + t * 3 + 2];
    }
    const int cmap[21] = {0,1,2,3,4,5,6, 7,8,9,10,11,12,13, 28,29,30,31,32,33,34};

    // ---- f MLP on xi[:, t=1, :] ----
    float f1[35];
#pragma unroll
    for (int j = 0; j < 35; ++j) {
        float acc = bl1[j];
#pragma unroll
        for (int c = 0; c < 21; ++c) acc = fmaf(u[1][c], Wl1[j * 35 + cmap[c]], acc);
        f1[j] = fmaxf(acc, 0.0f);
    }
    float f2[35];
#pragma unroll
    for (int j = 0; j < 35; ++j) {
        float acc = bl2[j];
#pragma unroll
        for (int k = 0; k < 35; ++k) acc = fmaf(f1[k], Wl2[j * 35 + k], acc);
        f2[j] = fmaxf(acc, 0.0f);
    }
    float fv = bl3[0];
#pragma unroll
    for (int k = 0; k < 35; ++k) fv = fmaf(f2[k], Wl3[k], fv);
    fv = fmaxf(fv, 0.0f);

    // ---- GRU_c, t = 0 (hc = 0) ----
    float hc[16];
#pragma unroll
    for (int j = 0; j < 16; ++j) {
        float ir = bihc[j], iz = bihc[16 + j], inn = bihc[32 + j];
#pragma unroll
        for (int c = 0; c < 21; ++c) {
            ir  = fmaf(u[0][c], Wihc[j * 35 + cmap[c]], ir);
            iz  = fmaf(u[0][c], Wihc[(16 + j) * 35 + cmap[c]], iz);
            inn = fmaf(u[0][c], Wihc[(32 + j) * 35 + cmap[c]], inn);
        }
        float r  = fsig(ir + bhhc[j]);
        float z  = fsig(iz + bhhc[16 + j]);
        float nn = ftanh(inn + r * bhhc[32 + j]);
        hc[j] = (1.0f - z) * nn;
    }
    // ---- GRU_c, t = 1 ----
    {
        float hnew[16];
#pragma unroll
        for (int j = 0; j < 16; ++j) {
            float ir = bihc[j], iz = bihc[16 + j], inn = bihc[32 + j];
#pragma unroll
            for (int c = 0; c < 21; ++c) {
                ir  = fmaf(u[1][c], Wihc[j * 35 + cmap[c]], ir);
                iz  = fmaf(u[1][c], Wihc[(16 + j) * 35 + cmap[c]], iz);
                inn = fmaf(u[1][c], Wihc[(32 + j) * 35 + cmap[c]], inn);
            }
            float hr = bhhc[j], hz = bhhc[16 + j], hn = bhhc[32 + j];
#pragma unroll
            for (int k = 0; k < 16; ++k) {
                hr = fmaf(hc[k], Whhc[j * 16 + k], hr);
                hz = fmaf(hc[k], Whhc[(16 + j) * 16 + k], hz);
                hn = fmaf(hc[k], Whhc[(32 + j) * 16 + k], hn);
            }
            float r  = fsig(ir + hr);
            float z  = fsig(iz + hz);
            float nn = ftanh(inn + r * hn);
            hnew[j] = (1.0f - z) * nn + z * hc[j];
        }
#pragma unroll
        for (int j = 0; j < 16; ++j) hc[j] = hnew[j];
    }

    // ---- qc MLP ----
    float v1[16];
#pragma unroll
    for (int j = 0; j < 16; ++j) {
        float acc = bc1[j];
#pragma unroll
        for (int k = 0; k < 16; ++k) acc = fmaf(hc[k], Wc1[j * 16 + k], acc);
        v1[j] = fmaxf(acc, 0.0f);
    }
    float v2[16];
#pragma unroll
    for (int j = 0; j < 16; ++j) {
        float acc = bc2[j];
#pragma unroll
        for (int k = 0; k < 16; ++k) acc = fmaf(v1[k], Wc2[j * 16 + k], acc);
        v2[j] = fmaxf(acc, 0.0f);
    }
    float qv = bc3[0];
#pragma unroll
    for (int k = 0; k < 16; ++k) qv = fmaf(v2[k], Wc3[k], qv);
    qv = fmaxf(qv, 0.0f);

    out1[b] = fv + qv;
}

extern "C" void kernel_launch(void* const* d_in, const int* in_sizes, int n_in,
                              void* d_out, int out_size, void* d_ws, size_t ws_size,
                              hipStream_t stream)
{
    const float* x    = (const float*)d_in[0];
    const float* Wih  = (const float*)d_in[1];
    const float* Whh  = (const float*)d_in[2];
    const float* bih  = (const float*)d_in[3];
    const float* bhh  = (const float*)d_in[4];
    const float* Wa1  = (const float*)d_in[5];
    const float* ba1  = (const float*)d_in[6];
    const float* Wa2  = (const float*)d_in[7];
    const float* ba2  = (const float*)d_in[8];
    const float* Wa3  = (const float*)d_in[9];
    const float* ba3  = (const float*)d_in[10];
    const float* Wl1  = (const float*)d_in[11];
    const float* bl1  = (const float*)d_in[12];
    const float* Wl2  = (const float*)d_in[13];
    const float* bl2  = (const float*)d_in[14];
    const float* Wl3  = (const float*)d_in[15];
    const float* bl3  = (const float*)d_in[16];
    const float* Wihc = (const float*)d_in[17];
    const float* Whhc = (const float*)d_in[18];
    const float* bihc = (const float*)d_in[19];
    const float* bhhc = (const float*)d_in[20];
    const float* Wc1  = (const float*)d_in[21];
    const float* bc1  = (const float*)d_in[22];
    const float* Wc2  = (const float*)d_in[23];
    const float* bc2  = (const float*)d_in[24];
    const float* Wc3  = (const float*)d_in[25];
    const float* bc3  = (const float*)d_in[26];

    float* out0 = (float*)d_out;                    // p[:, -1, :]  (B*N)
    float* out1 = out0 + (size_t)Bn * Nn;           // q            (B)
    float* pbuf = (float*)d_ws;                     // B*6 floats: p at n2 in {99,89,98}, t2 in {0,1}

    dim3 g1(Bn / 256, Nn);
    stage1_kernel<<<g1, 256, 0, stream>>>(x, Wih, Whh, bih, bhh,
                                          Wa1, ba1, Wa2, ba2, Wa3, ba3,
                                          out0, pbuf);
    stage2_kernel<<<Bn / 256, 256, 0, stream>>>(x, pbuf,
                                                Wl1, bl1, Wl2, bl2, Wl3, bl3,
                                                Wihc, Whhc, bihc, bhhc,
                                                Wc1, bc1, Wc2, bc2, Wc3, bc3,
                                                out1);
}

// Round 2
// 441.861 us; speedup vs baseline: 1.0929x; 1.0929x over previous
//
#include <hip/hip_runtime.h>

#define Bn 16384
#define Tn 2
#define Nn 100
#define Sn 6
#define Hn 16
#define ITEMS 2   // batch items per thread; weights loaded once, reused ITEMS x

__device__ __forceinline__ float frcp(float v) { return __builtin_amdgcn_rcpf(v); }
__device__ __forceinline__ float fsig(float v) { return frcp(1.0f + __expf(-v)); }
__device__ __forceinline__ float ftanh(float v) {
    v = fminf(fmaxf(v, -15.0f), 15.0f);
    float e = __expf(-2.0f * v);
    return (1.0f - e) * frcp(1.0f + e);
}

// 3-layer head MLP on IT items simultaneously: weights loaded once (float4 rows)
template<int IT>
__device__ __forceinline__ void head_mlp_multi(
    const float (&h)[IT][16],
    const float* __restrict__ wa1, const float* __restrict__ b1,
    const float* __restrict__ wa2, const float* __restrict__ b2,
    const float* __restrict__ wa3, float b3,
    float (&out)[IT])
{
    float v1[IT][16];
#pragma unroll
    for (int j = 0; j < 16; ++j) {
        const float4* r4 = (const float4*)(wa1 + j * 16);
        float4 w0 = r4[0], w1 = r4[1], w2 = r4[2], w3 = r4[3];
        float bj = b1[j];
#pragma unroll
        for (int i = 0; i < IT; ++i) {
            float acc = bj;
            acc = fmaf(h[i][0], w0.x, acc);  acc = fmaf(h[i][1], w0.y, acc);
            acc = fmaf(h[i][2], w0.z, acc);  acc = fmaf(h[i][3], w0.w, acc);
            acc = fmaf(h[i][4], w1.x, acc);  acc = fmaf(h[i][5], w1.y, acc);
            acc = fmaf(h[i][6], w1.z, acc);  acc = fmaf(h[i][7], w1.w, acc);
            acc = fmaf(h[i][8], w2.x, acc);  acc = fmaf(h[i][9], w2.y, acc);
            acc = fmaf(h[i][10], w2.z, acc); acc = fmaf(h[i][11], w2.w, acc);
            acc = fmaf(h[i][12], w3.x, acc); acc = fmaf(h[i][13], w3.y, acc);
            acc = fmaf(h[i][14], w3.z, acc); acc = fmaf(h[i][15], w3.w, acc);
            v1[i][j] = fmaxf(acc, 0.0f);
        }
    }
    float v2[IT][16];
#pragma unroll
    for (int j = 0; j < 16; ++j) {
        const float4* r4 = (const float4*)(wa2 + j * 16);
        float4 w0 = r4[0], w1 = r4[1], w2 = r4[2], w3 = r4[3];
        float bj = b2[j];
#pragma unroll
        for (int i = 0; i < IT; ++i) {
            float acc = bj;
            acc = fmaf(v1[i][0], w0.x, acc);  acc = fmaf(v1[i][1], w0.y, acc);
            acc = fmaf(v1[i][2], w0.z, acc);  acc = fmaf(v1[i][3], w0.w, acc);
            acc = fmaf(v1[i][4], w1.x, acc);  acc = fmaf(v1[i][5], w1.y, acc);
            acc = fmaf(v1[i][6], w1.z, acc);  acc = fmaf(v1[i][7], w1.w, acc);
            acc = fmaf(v1[i][8], w2.x, acc);  acc = fmaf(v1[i][9], w2.y, acc);
            acc = fmaf(v1[i][10], w2.z, acc); acc = fmaf(v1[i][11], w2.w, acc);
            acc = fmaf(v1[i][12], w3.x, acc); acc = fmaf(v1[i][13], w3.y, acc);
            acc = fmaf(v1[i][14], w3.z, acc); acc = fmaf(v1[i][15], w3.w, acc);
            v2[i][j] = fmaxf(acc, 0.0f);
        }
    }
    {
        const float4* r4 = (const float4*)(wa3);
        float4 w0 = r4[0], w1 = r4[1], w2 = r4[2], w3 = r4[3];
#pragma unroll
        for (int i = 0; i < IT; ++i) {
            float acc = b3;
            acc = fmaf(v2[i][0], w0.x, acc);  acc = fmaf(v2[i][1], w0.y, acc);
            acc = fmaf(v2[i][2], w0.z, acc);  acc = fmaf(v2[i][3], w0.w, acc);
            acc = fmaf(v2[i][4], w1.x, acc);  acc = fmaf(v2[i][5], w1.y, acc);
            acc = fmaf(v2[i][6], w1.z, acc);  acc = fmaf(v2[i][7], w1.w, acc);
            acc = fmaf(v2[i][8], w2.x, acc);  acc = fmaf(v2[i][9], w2.y, acc);
            acc = fmaf(v2[i][10], w2.z, acc); acc = fmaf(v2[i][11], w2.w, acc);
            acc = fmaf(v2[i][12], w3.x, acc); acc = fmaf(v2[i][13], w3.y, acc);
            acc = fmaf(v2[i][14], w3.z, acc); acc = fmaf(v2[i][15], w3.w, acc);
            out[i] = fmaxf(acc, 0.0f);
        }
    }
}

__global__ __launch_bounds__(256) void stage1_kernel(
    const float* __restrict__ x,
    const float* __restrict__ Wih, const float* __restrict__ Whh,
    const float* __restrict__ bih, const float* __restrict__ bhh,
    const float* __restrict__ Wa1, const float* __restrict__ ba1,
    const float* __restrict__ Wa2, const float* __restrict__ ba2,
    const float* __restrict__ Wa3, const float* __restrict__ ba3,
    float* __restrict__ out0, float* __restrict__ pbuf)
{
    const int n = blockIdx.y;
    const int tid = threadIdx.x;
    const int bbase = blockIdx.x * (256 * ITEMS) + tid;   // item i -> b = bbase + i*256

    const float* wih = Wih + n * 288;
    const float* whh = Whh + n * 768;
    const float* bi  = bih + n * 48;
    const float* bh  = bhh + n * 48;
    const float* wa1 = Wa1 + n * 256;
    const float* wa2 = Wa2 + n * 256;
    const float* wa3 = Wa3 + n * 16;
    const float* bb1 = ba1 + n * 16;
    const float* bb2 = ba2 + n * 16;
    const float  bb3 = ba3[n];

    // x[b, t, n, 0:6]  (24B chunks, float2-aligned)
    float xv[ITEMS][2][6];
#pragma unroll
    for (int i = 0; i < ITEMS; ++i) {
        const float* xb = x + (size_t)(bbase + i * 256) * (Tn * Nn * Sn) + n * Sn;
#pragma unroll
        for (int t = 0; t < 2; ++t) {
            const float2* p2 = (const float2*)(xb + t * (Nn * Sn));
            float2 a = p2[0], c = p2[1], d = p2[2];
            xv[i][t][0] = a.x; xv[i][t][1] = a.y;
            xv[i][t][2] = c.x; xv[i][t][3] = c.y;
            xv[i][t][4] = d.x; xv[i][t][5] = d.y;
        }
    }

    float h[ITEMS][16];
    float out_t0[ITEMS], out_t1[ITEMS];

    // ---- t = 0 : h_prev == 0 -> gh = b_hh ----
#pragma unroll
    for (int j = 0; j < 16; ++j) {
        // three gate rows of W_ih (6 floats each, float2-aligned)
        const float2* wr2 = (const float2*)(wih + j * 6);
        const float2* wz2 = (const float2*)(wih + (16 + j) * 6);
        const float2* wn2 = (const float2*)(wih + (32 + j) * 6);
        float2 wr0 = wr2[0], wr1 = wr2[1], wr2v = wr2[2];
        float2 wz0 = wz2[0], wz1 = wz2[1], wz2v = wz2[2];
        float2 wn0 = wn2[0], wn1 = wn2[1], wn2vv = wn2[2];
        float bij = bi[j], bizj = bi[16 + j], binj = bi[32 + j];
        float bhj = bh[j], bhzj = bh[16 + j], bhnj = bh[32 + j];
#pragma unroll
        for (int i = 0; i < ITEMS; ++i) {
            float ir = bij, iz = bizj, inn = binj;
            ir = fmaf(xv[i][0][0], wr0.x, ir); ir = fmaf(xv[i][0][1], wr0.y, ir);
            ir = fmaf(xv[i][0][2], wr1.x, ir); ir = fmaf(xv[i][0][3], wr1.y, ir);
            ir = fmaf(xv[i][0][4], wr2v.x, ir); ir = fmaf(xv[i][0][5], wr2v.y, ir);
            iz = fmaf(xv[i][0][0], wz0.x, iz); iz = fmaf(xv[i][0][1], wz0.y, iz);
            iz = fmaf(xv[i][0][2], wz1.x, iz); iz = fmaf(xv[i][0][3], wz1.y, iz);
            iz = fmaf(xv[i][0][4], wz2v.x, iz); iz = fmaf(xv[i][0][5], wz2v.y, iz);
            inn = fmaf(xv[i][0][0], wn0.x, inn); inn = fmaf(xv[i][0][1], wn0.y, inn);
            inn = fmaf(xv[i][0][2], wn1.x, inn); inn = fmaf(xv[i][0][3], wn1.y, inn);
            inn = fmaf(xv[i][0][4], wn2vv.x, inn); inn = fmaf(xv[i][0][5], wn2vv.y, inn);
            float r  = fsig(ir + bhj);
            float z  = fsig(iz + bhzj);
            float nn = ftanh(inn + r * bhnj);
            h[i][j] = (1.0f - z) * nn;
        }
    }
    head_mlp_multi<ITEMS>(h, wa1, bb1, wa2, bb2, wa3, bb3, out_t0);

    // ---- t = 1 ----
    {
        float hnew[ITEMS][16];
#pragma unroll
        for (int j = 0; j < 16; ++j) {
            const float2* wr2 = (const float2*)(wih + j * 6);
            const float2* wz2 = (const float2*)(wih + (16 + j) * 6);
            const float2* wn2 = (const float2*)(wih + (32 + j) * 6);
            float2 wr0 = wr2[0], wr1 = wr2[1], wr2v = wr2[2];
            float2 wz0 = wz2[0], wz1 = wz2[1], wz2v = wz2[2];
            float2 wn0 = wn2[0], wn1 = wn2[1], wn2vv = wn2[2];
            float bij = bi[j], bizj = bi[16 + j], binj = bi[32 + j];
            float bhj = bh[j], bhzj = bh[16 + j], bhnj = bh[32 + j];
            // W_hh rows (16 floats, float4-aligned)
            const float4* hr4 = (const float4*)(whh + j * 16);
            const float4* hz4 = (const float4*)(whh + (16 + j) * 16);
            const float4* hn4 = (const float4*)(whh + (32 + j) * 16);
            float4 hr0 = hr4[0], hr1 = hr4[1], hr2 = hr4[2], hr3 = hr4[3];
            float4 hz0 = hz4[0], hz1 = hz4[1], hz2 = hz4[2], hz3 = hz4[3];
            float4 hn0 = hn4[0], hn1 = hn4[1], hn2 = hn4[2], hn3 = hn4[3];
#pragma unroll
            for (int i = 0; i < ITEMS; ++i) {
                float ir = bij, iz = bizj, inn = binj;
                ir = fmaf(xv[i][1][0], wr0.x, ir); ir = fmaf(xv[i][1][1], wr0.y, ir);
                ir = fmaf(xv[i][1][2], wr1.x, ir); ir = fmaf(xv[i][1][3], wr1.y, ir);
                ir = fmaf(xv[i][1][4], wr2v.x, ir); ir = fmaf(xv[i][1][5], wr2v.y, ir);
                iz = fmaf(xv[i][1][0], wz0.x, iz); iz = fmaf(xv[i][1][1], wz0.y, iz);
                iz = fmaf(xv[i][1][2], wz1.x, iz); iz = fmaf(xv[i][1][3], wz1.y, iz);
                iz = fmaf(xv[i][1][4], wz2v.x, iz); iz = fmaf(xv[i][1][5], wz2v.y, iz);
                inn = fmaf(xv[i][1][0], wn0.x, inn); inn = fmaf(xv[i][1][1], wn0.y, inn);
                inn = fmaf(xv[i][1][2], wn1.x, inn); inn = fmaf(xv[i][1][3], wn1.y, inn);
                inn = fmaf(xv[i][1][4], wn2vv.x, inn); inn = fmaf(xv[i][1][5], wn2vv.y, inn);

                float hr = bhj, hz = bhzj, hn = bhnj;
                hr = fmaf(h[i][0], hr0.x, hr);  hr = fmaf(h[i][1], hr0.y, hr);
                hr = fmaf(h[i][2], hr0.z, hr);  hr = fmaf(h[i][3], hr0.w, hr);
                hr = fmaf(h[i][4], hr1.x, hr);  hr = fmaf(h[i][5], hr1.y, hr);
                hr = fmaf(h[i][6], hr1.z, hr);  hr = fmaf(h[i][7], hr1.w, hr);
                hr = fmaf(h[i][8], hr2.x, hr);  hr = fmaf(h[i][9], hr2.y, hr);
                hr = fmaf(h[i][10], hr2.z, hr); hr = fmaf(h[i][11], hr2.w, hr);
                hr = fmaf(h[i][12], hr3.x, hr); hr = fmaf(h[i][13], hr3.y, hr);
                hr = fmaf(h[i][14], hr3.z, hr); hr = fmaf(h[i][15], hr3.w, hr);
                hz = fmaf(h[i][0], hz0.x, hz);  hz = fmaf(h[i][1], hz0.y, hz);
                hz = fmaf(h[i][2], hz0.z, hz);  hz = fmaf(h[i][3], hz0.w, hz);
                hz = fmaf(h[i][4], hz1.x, hz);  hz = fmaf(h[i][5], hz1.y, hz);
                hz = fmaf(h[i][6], hz1.z, hz);  hz = fmaf(h[i][7], hz1.w, hz);
                hz = fmaf(h[i][8], hz2.x, hz);  hz = fmaf(h[i][9], hz2.y, hz);
                hz = fmaf(h[i][10], hz2.z, hz); hz = fmaf(h[i][11], hz2.w, hz);
                hz = fmaf(h[i][12], hz3.x, hz); hz = fmaf(h[i][13], hz3.y, hz);
                hz = fmaf(h[i][14], hz3.z, hz); hz = fmaf(h[i][15], hz3.w, hz);
                hn = fmaf(h[i][0], hn0.x, hn);  hn = fmaf(h[i][1], hn0.y, hn);
                hn = fmaf(h[i][2], hn0.z, hn);  hn = fmaf(h[i][3], hn0.w, hn);
                hn = fmaf(h[i][4], hn1.x, hn);  hn = fmaf(h[i][5], hn1.y, hn);
                hn = fmaf(h[i][6], hn1.z, hn);  hn = fmaf(h[i][7], hn1.w, hn);
                hn = fmaf(h[i][8], hn2.x, hn);  hn = fmaf(h[i][9], hn2.y, hn);
                hn = fmaf(h[i][10], hn2.z, hn); hn = fmaf(h[i][11], hn2.w, hn);
                hn = fmaf(h[i][12], hn3.x, hn); hn = fmaf(h[i][13], hn3.y, hn);
                hn = fmaf(h[i][14], hn3.z, hn); hn = fmaf(h[i][15], hn3.w, hn);

                float r  = fsig(ir + hr);
                float z  = fsig(iz + hz);
                float nn = ftanh(inn + r * hn);
                hnew[i][j] = (1.0f - z) * nn + z * h[i][j];
            }
        }
#pragma unroll
        for (int i = 0; i < ITEMS; ++i)
#pragma unroll
            for (int j = 0; j < 16; ++j) h[i][j] = hnew[i][j];
    }
    head_mlp_multi<ITEMS>(h, wa1, bb1, wa2, bb2, wa3, bb3, out_t1);

    // ---- scatter through the transpose/reshape permutation ----
    // a[b,t,n] flat k0 = n*B*T + b*T + t; p[b2,t2,n2] = flat[b2*200 + t2*100 + n2]
#pragma unroll
    for (int i = 0; i < ITEMS; ++i) {
        const unsigned b = (unsigned)(bbase + i * 256);
#pragma unroll
        for (int t = 0; t < 2; ++t) {
            unsigned k0 = (unsigned)n * (Bn * Tn) + b * 2u + (unsigned)t;
            unsigned b2 = k0 / 200u;
            unsigned r  = k0 - b2 * 200u;
            unsigned t2 = (r >= 100u) ? 1u : 0u;
            unsigned n2 = r - t2 * 100u;
            float v = (t == 0) ? out_t0[i] : out_t1[i];
            if (t2) out0[b2 * 100u + n2] = v;
            if (n2 == 99u)      pbuf[b2 * 6u + t2 * 3u + 0u] = v;
            else if (n2 == 89u) pbuf[b2 * 6u + t2 * 3u + 1u] = v;
            else if (n2 == 98u) pbuf[b2 * 6u + t2 * 3u + 2u] = v;
        }
    }
}

__global__ __launch_bounds__(256) void stage2_kernel(
    const float* __restrict__ x, const float* __restrict__ pbuf,
    const float* __restrict__ Wl1, const float* __restrict__ bl1,
    const float* __restrict__ Wl2, const float* __restrict__ bl2,
    const float* __restrict__ Wl3, const float* __restrict__ bl3,
    const float* __restrict__ Wihc, const float* __restrict__ Whhc,
    const float* __restrict__ bihc, const float* __restrict__ bhhc,
    const float* __restrict__ Wc1, const float* __restrict__ bc1,
    const float* __restrict__ Wc2, const float* __restrict__ bc2,
    const float* __restrict__ Wc3, const float* __restrict__ bc3,
    float* __restrict__ out1)
{
    const int b = blockIdx.x * 256 + threadIdx.x;
    if (b >= Bn) return;

    // xi nonzero columns: 0..6 -> ch99, 7..13 -> ch89, 28..34 -> ch98 (14..27 zero)
    float u[2][21];
#pragma unroll
    for (int t = 0; t < 2; ++t) {
        const float* xb = x + (size_t)b * (Tn * Nn * Sn) + t * (Nn * Sn);
#pragma unroll
        for (int s = 0; s < 6; ++s) {
            u[t][s]      = xb[99 * 6 + s];
            u[t][7 + s]  = xb[89 * 6 + s];
            u[t][14 + s] = xb[98 * 6 + s];
        }
        u[t][6]  = pbuf[b * 6 + t * 3 + 0];
        u[t][13] = pbuf[b * 6 + t * 3 + 1];
        u[t][20] = pbuf[b * 6 + t * 3 + 2];
    }
    const int cmap[21] = {0,1,2,3,4,5,6, 7,8,9,10,11,12,13, 28,29,30,31,32,33,34};

    float f1[35];
#pragma unroll
    for (int j = 0; j < 35; ++j) {
        float acc = bl1[j];
#pragma unroll
        for (int c = 0; c < 21; ++c) acc = fmaf(u[1][c], Wl1[j * 35 + cmap[c]], acc);
        f1[j] = fmaxf(acc, 0.0f);
    }
    float f2[35];
#pragma unroll
    for (int j = 0; j < 35; ++j) {
        float acc = bl2[j];
#pragma unroll
        for (int k = 0; k < 35; ++k) acc = fmaf(f1[k], Wl2[j * 35 + k], acc);
        f2[j] = fmaxf(acc, 0.0f);
    }
    float fv = bl3[0];
#pragma unroll
    for (int k = 0; k < 35; ++k) fv = fmaf(f2[k], Wl3[k], fv);
    fv = fmaxf(fv, 0.0f);

    float hc[16];
#pragma unroll
    for (int j = 0; j < 16; ++j) {
        float ir = bihc[j], iz = bihc[16 + j], inn = bihc[32 + j];
#pragma unroll
        for (int c = 0; c < 21; ++c) {
            ir  = fmaf(u[0][c], Wihc[j * 35 + cmap[c]], ir);
            iz  = fmaf(u[0][c], Wihc[(16 + j) * 35 + cmap[c]], iz);
            inn = fmaf(u[0][c], Wihc[(32 + j) * 35 + cmap[c]], inn);
        }
        float r  = fsig(ir + bhhc[j]);
        float z  = fsig(iz + bhhc[16 + j]);
        float nn = ftanh(inn + r * bhhc[32 + j]);
        hc[j] = (1.0f - z) * nn;
    }
    {
        float hnew[16];
#pragma unroll
        for (int j = 0; j < 16; ++j) {
            float ir = bihc[j], iz = bihc[16 + j], inn = bihc[32 + j];
#pragma unroll
            for (int c = 0; c < 21; ++c) {
                ir  = fmaf(u[1][c], Wihc[j * 35 + cmap[c]], ir);
                iz  = fmaf(u[1][c], Wihc[(16 + j) * 35 + cmap[c]], iz);
                inn = fmaf(u[1][c], Wihc[(32 + j) * 35 + cmap[c]], inn);
            }
            float hr = bhhc[j], hz = bhhc[16 + j], hn = bhhc[32 + j];
#pragma unroll
            for (int k = 0; k < 16; ++k) {
                hr = fmaf(hc[k], Whhc[j * 16 + k], hr);
                hz = fmaf(hc[k], Whhc[(16 + j) * 16 + k], hz);
                hn = fmaf(hc[k], Whhc[(32 + j) * 16 + k], hn);
            }
            float r  = fsig(ir + hr);
            float z  = fsig(iz + hz);
            float nn = ftanh(inn + r * hn);
            hnew[j] = (1.0f - z) * nn + z * hc[j];
        }
#pragma unroll
        for (int j = 0; j < 16; ++j) hc[j] = hnew[j];
    }

    float v1[16];
#pragma unroll
    for (int j = 0; j < 16; ++j) {
        float acc = bc1[j];
#pragma unroll
        for (int k = 0; k < 16; ++k) acc = fmaf(hc[k], Wc1[j * 16 + k], acc);
        v1[j] = fmaxf(acc, 0.0f);
    }
    float v2[16];
#pragma unroll
    for (int j = 0; j < 16; ++j) {
        float acc = bc2[j];
#pragma unroll
        for (int k = 0; k < 16; ++k) acc = fmaf(v1[k], Wc2[j * 16 + k], acc);
        v2[j] = fmaxf(acc, 0.0f);
    }
    float qv = bc3[0];
#pragma unroll
    for (int k = 0; k < 16; ++k) qv = fmaf(v2[k], Wc3[k], qv);
    qv = fmaxf(qv, 0.0f);

    out1[b] = fv + qv;
}

extern "C" void kernel_launch(void* const* d_in, const int* in_sizes, int n_in,
                              void* d_out, int out_size, void* d_ws, size_t ws_size,
                              hipStream_t stream)
{
    const float* x    = (const float*)d_in[0];
    const float* Wih  = (const float*)d_in[1];
    const float* Whh  = (const float*)d_in[2];
    const float* bih  = (const float*)d_in[3];
    const float* bhh  = (const float*)d_in[4];
    const float* Wa1  = (const float*)d_in[5];
    const float* ba1  = (const float*)d_in[6];
    const float* Wa2  = (const float*)d_in[7];
    const float* ba2  = (const float*)d_in[8];
    const float* Wa3  = (const float*)d_in[9];
    const float* ba3  = (const float*)d_in[10];
    const float* Wl1  = (const float*)d_in[11];
    const float* bl1  = (const float*)d_in[12];
    const float* Wl2  = (const float*)d_in[13];
    const float* bl2  = (const float*)d_in[14];
    const float* Wl3  = (const float*)d_in[15];
    const float* bl3  = (const float*)d_in[16];
    const float* Wihc = (const float*)d_in[17];
    const float* Whhc = (const float*)d_in[18];
    const float* bihc = (const float*)d_in[19];
    const float* bhhc = (const float*)d_in[20];
    const float* Wc1  = (const float*)d_in[21];
    const float* bc1  = (const float*)d_in[22];
    const float* Wc2  = (const float*)d_in[23];
    const float* bc2  = (const float*)d_in[24];
    const float* Wc3  = (const float*)d_in[25];
    const float* bc3  = (const float*)d_in[26];

    float* out0 = (float*)d_out;                    // p[:, -1, :]  (B*N)
    float* out1 = out0 + (size_t)Bn * Nn;           // q            (B)
    float* pbuf = (float*)d_ws;                     // B*6 floats

    dim3 g1(Bn / (256 * ITEMS), Nn);
    stage1_kernel<<<g1, 256, 0, stream>>>(x, Wih, Whh, bih, bhh,
                                          Wa1, ba1, Wa2, ba2, Wa3, ba3,
                                          out0, pbuf);
    stage2_kernel<<<Bn / 256, 256, 0, stream>>>(x, pbuf,
                                                Wl1, bl1, Wl2, bl2, Wl3, bl3,
                                                Wihc, Whhc, bihc, bhhc,
                                                Wc1, bc1, Wc2, bc2, Wc3, bc3,
                                                out1);
}

// Round 3
// 168.011 us; speedup vs baseline: 2.8744x; 2.6300x over previous
//
#include <hip/hip_runtime.h>

#define Bn 16384
#define Tn 2
#define Nn 100
#define Sn 6
#define Hn 16
#define BT 4   // batch tiles (of 16 items) per wave

typedef __attribute__((ext_vector_type(8))) short short8;   // 8 x bf16 MFMA frag
typedef __attribute__((ext_vector_type(4))) float f32x4;    // MFMA accum

__device__ __forceinline__ float frcp(float v) { return __builtin_amdgcn_rcpf(v); }
__device__ __forceinline__ float fsig(float v) { return frcp(1.0f + __expf(-v)); }
__device__ __forceinline__ float ftanh(float v) {
    v = fminf(fmaxf(v, -15.0f), 15.0f);
    float e = __expf(-2.0f * v);
    return (1.0f - e) * frcp(1.0f + e);
}

// pack 2 f32 -> 2 bf16 (RNE), lo = a, hi = b
__device__ __forceinline__ unsigned pkbf(float a, float b) {
    unsigned r;
    asm("v_cvt_pk_bf16_f32 %0, %1, %2" : "=v"(r) : "v"(a), "v"(b));
    return r;
}

__device__ __forceinline__ short8 mk_frag(unsigned a, unsigned b, unsigned c, unsigned d) {
    union { unsigned u[4]; short8 s; } x;
    x.u[0] = a; x.u[1] = b; x.u[2] = c; x.u[3] = d;
    return x.s;
}

__device__ __forceinline__ unsigned shflu(unsigned v, int src) {
    return (unsigned)__shfl((int)v, src, 64);
}

// Build B-frag for a K=16 operand held in C-layout (lane s: item s&15, chans (s>>4)*4+r).
// B-lane l (g=l>>4, m=l&15) needs h[m][k], k=g*8+jj.  k>>2 selects source group,
// k&3 selects pack (hp0: r0,r1 / hp1: r2,r3).
__device__ __forceinline__ short8 buildK16(unsigned hp0, unsigned hp1, int g, int m) {
    int s0 = ((32 * g + m) & 63);
    int s1 = ((32 * g + 16 + m) & 63);
    unsigned r0 = shflu(hp0, s0);
    unsigned r1 = shflu(hp1, s0);
    unsigned r2 = shflu(hp0, s1);
    unsigned r3 = shflu(hp1, s1);
    if (g >= 2) { r0 = 0; r1 = 0; r2 = 0; r3 = 0; }
    return mk_frag(r0, r1, r2, r3);
}

// A-frag for a row-major [16][16] weight: lane row = l&15, k = g*8+jj
__device__ __forceinline__ short8 loadA16(const float* __restrict__ w, int g, int jr) {
    if (g < 2) {
        const float4* q = (const float4*)(w + jr * 16 + g * 8);
        float4 q0 = q[0], q1 = q[1];
        return mk_frag(pkbf(q0.x, q0.y), pkbf(q0.z, q0.w),
                       pkbf(q1.x, q1.y), pkbf(q1.z, q1.w));
    }
    return mk_frag(0u, 0u, 0u, 0u);
}

// A-frag for a row-major [16][6] weight (K=6 at k0..5): only group 0 nonzero
__device__ __forceinline__ short8 loadA6(const float* __restrict__ w, int g, int jr) {
    if (g == 0) {
        const float2* q = (const float2*)(w + jr * 6);
        float2 a = q[0], b = q[1], c = q[2];
        return mk_frag(pkbf(a.x, a.y), pkbf(b.x, b.y), pkbf(c.x, c.y), 0u);
    }
    return mk_frag(0u, 0u, 0u, 0u);
}

__global__ __launch_bounds__(256) void stage1_mfma(
    const float* __restrict__ x,
    const float* __restrict__ Wih, const float* __restrict__ Whh,
    const float* __restrict__ bih, const float* __restrict__ bhh,
    const float* __restrict__ Wa1, const float* __restrict__ ba1,
    const float* __restrict__ Wa2, const float* __restrict__ ba2,
    const float* __restrict__ Wa3, const float* __restrict__ ba3,
    float* __restrict__ out0, float* __restrict__ pbuf)
{
    const int n = blockIdx.y;
    const int l = threadIdx.x & 63;
    const int w = threadIdx.x >> 6;
    const int g = l >> 4;     // lane group (k-group / channel group)
    const int m = l & 15;     // batch item within tile (as B-col / C-col)
    const int wave_base = (blockIdx.x * 4 + w) * (16 * BT);

    // ---- persistent A-frags (weights, bf16) ----
    short8 Aih0 = loadA6(Wih + n * 288 +  0 * 6, g, m);   // gate r rows 0-15
    short8 Aih1 = loadA6(Wih + n * 288 + 16 * 6, g, m);   // gate z rows 16-31
    short8 Aih2 = loadA6(Wih + n * 288 + 32 * 6, g, m);   // gate n rows 32-47
    short8 Ahh0 = loadA16(Whh + n * 768 +   0, g, m);
    short8 Ahh1 = loadA16(Whh + n * 768 + 256, g, m);
    short8 Ahh2 = loadA16(Whh + n * 768 + 512, g, m);
    short8 Aa1  = loadA16(Wa1 + n * 256, g, m);
    short8 Aa2  = loadA16(Wa2 + n * 256, g, m);

    // ---- biases: per-lane float4 covering channels j = g*4 .. g*4+3 ----
    float4 bi0 = *(const float4*)(bih + n * 48 +  0 + g * 4);
    float4 bi1 = *(const float4*)(bih + n * 48 + 16 + g * 4);
    float4 bi2 = *(const float4*)(bih + n * 48 + 32 + g * 4);
    float4 bh0 = *(const float4*)(bhh + n * 48 +  0 + g * 4);
    float4 bh1 = *(const float4*)(bhh + n * 48 + 16 + g * 4);
    float4 bh2 = *(const float4*)(bhh + n * 48 + 32 + g * 4);
    float4 vb1 = *(const float4*)(ba1 + n * 16 + g * 4);
    float4 vb2 = *(const float4*)(ba2 + n * 16 + g * 4);
    float4 vw3 = *(const float4*)(Wa3 + n * 16 + g * 4);
    const float ba3n = ba3[n];
    const float* bi0a = (const float*)&bi0; const float* bi1a = (const float*)&bi1;
    const float* bi2a = (const float*)&bi2; const float* bh0a = (const float*)&bh0;
    const float* bh1a = (const float*)&bh1; const float* bh2a = (const float*)&bh2;
    const float* vb1a = (const float*)&vb1; const float* vb2a = (const float*)&vb2;
    const float* vw3a = (const float*)&vw3;

    const f32x4 z4 = {0.0f, 0.0f, 0.0f, 0.0f};

    for (int it = 0; it < BT; ++it) {
        const int bb = wave_base + it * 16;

        // x rows of item m (all 4 groups load the same row; only g0 uses it)
        const float* xr = x + (size_t)(bb + m) * (Tn * Nn * Sn) + n * Sn;
        const float2* x0p = (const float2*)(xr);
        const float2* x1p = (const float2*)(xr + Nn * Sn);
        float2 x0a = x0p[0], x0b = x0p[1], x0c = x0p[2];
        float2 x1a = x1p[0], x1b = x1p[1], x1c = x1p[2];
        short8 Bx0 = (g == 0)
            ? mk_frag(pkbf(x0a.x, x0a.y), pkbf(x0b.x, x0b.y), pkbf(x0c.x, x0c.y), 0u)
            : mk_frag(0u, 0u, 0u, 0u);
        short8 Bx1 = (g == 0)
            ? mk_frag(pkbf(x1a.x, x1a.y), pkbf(x1b.x, x1b.y), pkbf(x1c.x, x1c.y), 0u)
            : mk_frag(0u, 0u, 0u, 0u);

        // ---- t = 0 : gi = Wih·x0ᵀ ; gh = b_hh only ----
        f32x4 Cr = __builtin_amdgcn_mfma_f32_16x16x32_bf16(Aih0, Bx0, z4, 0, 0, 0);
        f32x4 Cz = __builtin_amdgcn_mfma_f32_16x16x32_bf16(Aih1, Bx0, z4, 0, 0, 0);
        f32x4 Cn = __builtin_amdgcn_mfma_f32_16x16x32_bf16(Aih2, Bx0, z4, 0, 0, 0);
        float h0[4];
#pragma unroll
        for (int r = 0; r < 4; ++r) {
            float rr = fsig(Cr[r] + bi0a[r] + bh0a[r]);
            float zz = fsig(Cz[r] + bi1a[r] + bh1a[r]);
            float nn = ftanh(Cn[r] + bi2a[r] + rr * bh2a[r]);
            h0[r] = (1.0f - zz) * nn;
        }
        unsigned hp0 = pkbf(h0[0], h0[1]), hp1 = pkbf(h0[2], h0[3]);
        short8 Bh0 = buildK16(hp0, hp1, g, m);

        // ---- MLP t0 ----
        f32x4 C1 = __builtin_amdgcn_mfma_f32_16x16x32_bf16(Aa1, Bh0, z4, 0, 0, 0);
        float a1v[4];
#pragma unroll
        for (int r = 0; r < 4; ++r) a1v[r] = fmaxf(C1[r] + vb1a[r], 0.0f);
        short8 Ba1 = buildK16(pkbf(a1v[0], a1v[1]), pkbf(a1v[2], a1v[3]), g, m);
        f32x4 C2 = __builtin_amdgcn_mfma_f32_16x16x32_bf16(Aa2, Ba1, z4, 0, 0, 0);
        float part = 0.0f;
#pragma unroll
        for (int r = 0; r < 4; ++r) part += fmaxf(C2[r] + vb2a[r], 0.0f) * vw3a[r];
        part += __shfl_xor(part, 16, 64);
        part += __shfl_xor(part, 32, 64);
        float o0 = fmaxf(part + ba3n, 0.0f);

        // ---- t = 1 : gi = Wih·x1ᵀ ; gh = Whh·h0ᵀ ----
        Cr = __builtin_amdgcn_mfma_f32_16x16x32_bf16(Aih0, Bx1, z4, 0, 0, 0);
        Cr = __builtin_amdgcn_mfma_f32_16x16x32_bf16(Ahh0, Bh0, Cr, 0, 0, 0);
        Cz = __builtin_amdgcn_mfma_f32_16x16x32_bf16(Aih1, Bx1, z4, 0, 0, 0);
        Cz = __builtin_amdgcn_mfma_f32_16x16x32_bf16(Ahh1, Bh0, Cz, 0, 0, 0);
        f32x4 Cn1 = __builtin_amdgcn_mfma_f32_16x16x32_bf16(Aih2, Bx1, z4, 0, 0, 0);
        f32x4 Cn2 = __builtin_amdgcn_mfma_f32_16x16x32_bf16(Ahh2, Bh0, z4, 0, 0, 0);
        float h1[4];
#pragma unroll
        for (int r = 0; r < 4; ++r) {
            float rr = fsig(Cr[r] + bi0a[r] + bh0a[r]);
            float zz = fsig(Cz[r] + bi1a[r] + bh1a[r]);
            float nn = ftanh(Cn1[r] + bi2a[r] + rr * (Cn2[r] + bh2a[r]));
            h1[r] = (1.0f - zz) * nn + zz * h0[r];
        }
        short8 Bh1 = buildK16(pkbf(h1[0], h1[1]), pkbf(h1[2], h1[3]), g, m);

        // ---- MLP t1 ----
        C1 = __builtin_amdgcn_mfma_f32_16x16x32_bf16(Aa1, Bh1, z4, 0, 0, 0);
#pragma unroll
        for (int r = 0; r < 4; ++r) a1v[r] = fmaxf(C1[r] + vb1a[r], 0.0f);
        Ba1 = buildK16(pkbf(a1v[0], a1v[1]), pkbf(a1v[2], a1v[3]), g, m);
        C2 = __builtin_amdgcn_mfma_f32_16x16x32_bf16(Aa2, Ba1, z4, 0, 0, 0);
        part = 0.0f;
#pragma unroll
        for (int r = 0; r < 4; ++r) part += fmaxf(C2[r] + vb2a[r], 0.0f) * vw3a[r];
        part += __shfl_xor(part, 16, 64);
        part += __shfl_xor(part, 32, 64);
        float o1 = fmaxf(part + ba3n, 0.0f);

        // ---- scatter through the transpose/reshape permutation (lanes 0-15) ----
        if (g == 0) {
            const unsigned b = (unsigned)(bb + m);
#pragma unroll
            for (int t = 0; t < 2; ++t) {
                unsigned k0 = (unsigned)n * (Bn * Tn) + b * 2u + (unsigned)t;
                unsigned b2 = k0 / 200u;
                unsigned rr = k0 - b2 * 200u;
                unsigned t2 = (rr >= 100u) ? 1u : 0u;
                unsigned n2 = rr - t2 * 100u;
                float v = (t == 0) ? o0 : o1;
                if (t2) out0[b2 * 100u + n2] = v;
                if (n2 == 99u)      pbuf[b2 * 6u + t2 * 3u + 0u] = v;
                else if (n2 == 89u) pbuf[b2 * 6u + t2 * 3u + 1u] = v;
                else if (n2 == 98u) pbuf[b2 * 6u + t2 * 3u + 2u] = v;
            }
        }
    }
}

__global__ __launch_bounds__(64) void stage2_kernel(
    const float* __restrict__ x, const float* __restrict__ pbuf,
    const float* __restrict__ Wl1, const float* __restrict__ bl1,
    const float* __restrict__ Wl2, const float* __restrict__ bl2,
    const float* __restrict__ Wl3, const float* __restrict__ bl3,
    const float* __restrict__ Wihc, const float* __restrict__ Whhc,
    const float* __restrict__ bihc, const float* __restrict__ bhhc,
    const float* __restrict__ Wc1, const float* __restrict__ bc1,
    const float* __restrict__ Wc2, const float* __restrict__ bc2,
    const float* __restrict__ Wc3, const float* __restrict__ bc3,
    float* __restrict__ out1)
{
    const int b = blockIdx.x * 64 + threadIdx.x;
    if (b >= Bn) return;

    // xi nonzero columns: 0..6 -> ch99, 7..13 -> ch89, 28..34 -> ch98 (14..27 zero)
    float u[2][21];
#pragma unroll
    for (int t = 0; t < 2; ++t) {
        const float* xb = x + (size_t)b * (Tn * Nn * Sn) + t * (Nn * Sn);
#pragma unroll
        for (int s = 0; s < 6; ++s) {
            u[t][s]      = xb[99 * 6 + s];
            u[t][7 + s]  = xb[89 * 6 + s];
            u[t][14 + s] = xb[98 * 6 + s];
        }
        u[t][6]  = pbuf[b * 6 + t * 3 + 0];
        u[t][13] = pbuf[b * 6 + t * 3 + 1];
        u[t][20] = pbuf[b * 6 + t * 3 + 2];
    }
    const int cmap[21] = {0,1,2,3,4,5,6, 7,8,9,10,11,12,13, 28,29,30,31,32,33,34};

    float f1[35];
#pragma unroll
    for (int j = 0; j < 35; ++j) {
        float acc = bl1[j];
#pragma unroll
        for (int c = 0; c < 21; ++c) acc = fmaf(u[1][c], Wl1[j * 35 + cmap[c]], acc);
        f1[j] = fmaxf(acc, 0.0f);
    }
    float f2[35];
#pragma unroll
    for (int j = 0; j < 35; ++j) {
        float acc = bl2[j];
#pragma unroll
        for (int k = 0; k < 35; ++k) acc = fmaf(f1[k], Wl2[j * 35 + k], acc);
        f2[j] = fmaxf(acc, 0.0f);
    }
    float fv = bl3[0];
#pragma unroll
    for (int k = 0; k < 35; ++k) fv = fmaf(f2[k], Wl3[k], fv);
    fv = fmaxf(fv, 0.0f);

    float hc[16];
#pragma unroll
    for (int j = 0; j < 16; ++j) {
        float ir = bihc[j], iz = bihc[16 + j], inn = bihc[32 + j];
#pragma unroll
        for (int c = 0; c < 21; ++c) {
            ir  = fmaf(u[0][c], Wihc[j * 35 + cmap[c]], ir);
            iz  = fmaf(u[0][c], Wihc[(16 + j) * 35 + cmap[c]], iz);
            inn = fmaf(u[0][c], Wihc[(32 + j) * 35 + cmap[c]], inn);
        }
        float r  = fsig(ir + bhhc[j]);
        float z  = fsig(iz + bhhc[16 + j]);
        float nn = ftanh(inn + r * bhhc[32 + j]);
        hc[j] = (1.0f - z) * nn;
    }
    {
        float hnew[16];
#pragma unroll
        for (int j = 0; j < 16; ++j) {
            float ir = bihc[j], iz = bihc[16 + j], inn = bihc[32 + j];
#pragma unroll
            for (int c = 0; c < 21; ++c) {
                ir  = fmaf(u[1][c], Wihc[j * 35 + cmap[c]], ir);
                iz  = fmaf(u[1][c], Wihc[(16 + j) * 35 + cmap[c]], iz);
                inn = fmaf(u[1][c], Wihc[(32 + j) * 35 + cmap[c]], inn);
            }
            float hr = bhhc[j], hz = bhhc[16 + j], hn = bhhc[32 + j];
#pragma unroll
            for (int k = 0; k < 16; ++k) {
                hr = fmaf(hc[k], Whhc[j * 16 + k], hr);
                hz = fmaf(hc[k], Whhc[(16 + j) * 16 + k], hz);
                hn = fmaf(hc[k], Whhc[(32 + j) * 16 + k], hn);
            }
            float r  = fsig(ir + hr);
            float z  = fsig(iz + hz);
            float nn = ftanh(inn + r * hn);
            hnew[j] = (1.0f - z) * nn + z * hc[j];
        }
#pragma unroll
        for (int j = 0; j < 16; ++j) hc[j] = hnew[j];
    }

    float v1[16];
#pragma unroll
    for (int j = 0; j < 16; ++j) {
        float acc = bc1[j];
#pragma unroll
        for (int k = 0; k < 16; ++k) acc = fmaf(hc[k], Wc1[j * 16 + k], acc);
        v1[j] = fmaxf(acc, 0.0f);
    }
    float v2[16];
#pragma unroll
    for (int j = 0; j < 16; ++j) {
        float acc = bc2[j];
#pragma unroll
        for (int k = 0; k < 16; ++k) acc = fmaf(v1[k], Wc2[j * 16 + k], acc);
        v2[j] = fmaxf(acc, 0.0f);
    }
    float qv = bc3[0];
#pragma unroll
    for (int k = 0; k < 16; ++k) qv = fmaf(v2[k], Wc3[k], qv);
    qv = fmaxf(qv, 0.0f);

    out1[b] = fv + qv;
}

extern "C" void kernel_launch(void* const* d_in, const int* in_sizes, int n_in,
                              void* d_out, int out_size, void* d_ws, size_t ws_size,
                              hipStream_t stream)
{
    const float* x    = (const float*)d_in[0];
    const float* Wih  = (const float*)d_in[1];
    const float* Whh  = (const float*)d_in[2];
    const float* bih  = (const float*)d_in[3];
    const float* bhh  = (const float*)d_in[4];
    const float* Wa1  = (const float*)d_in[5];
    const float* ba1  = (const float*)d_in[6];
    const float* Wa2  = (const float*)d_in[7];
    const float* ba2  = (const float*)d_in[8];
    const float* Wa3  = (const float*)d_in[9];
    const float* ba3  = (const float*)d_in[10];
    const float* Wl1  = (const float*)d_in[11];
    const float* bl1  = (const float*)d_in[12];
    const float* Wl2  = (const float*)d_in[13];
    const float* bl2  = (const float*)d_in[14];
    const float* Wl3  = (const float*)d_in[15];
    const float* bl3  = (const float*)d_in[16];
    const float* Wihc = (const float*)d_in[17];
    const float* Whhc = (const float*)d_in[18];
    const float* bihc = (const float*)d_in[19];
    const float* bhhc = (const float*)d_in[20];
    const float* Wc1  = (const float*)d_in[21];
    const float* bc1  = (const float*)d_in[22];
    const float* Wc2  = (const float*)d_in[23];
    const float* bc2  = (const float*)d_in[24];
    const float* Wc3  = (const float*)d_in[25];
    const float* bc3  = (const float*)d_in[26];

    float* out0 = (float*)d_out;                    // p[:, -1, :]  (B*N)
    float* out1 = out0 + (size_t)Bn * Nn;           // q            (B)
    float* pbuf = (float*)d_ws;                     // B*6 floats

    dim3 g1(Bn / (16 * 4 * BT), Nn);                // 64 x 100 blocks, 4 waves each
    stage1_mfma<<<g1, 256, 0, stream>>>(x, Wih, Whh, bih, bhh,
                                        Wa1, ba1, Wa2, ba2, Wa3, ba3,
                                        out0, pbuf);
    stage2_kernel<<<Bn / 64, 64, 0, stream>>>(x, pbuf,
                                              Wl1, bl1, Wl2, bl2, Wl3, bl3,
                                              Wihc, Whhc, bihc, bhhc,
                                              Wc1, bc1, Wc2, bc2, Wc3, bc3,
                                              out1);
}